// Round 13
// baseline (200.182 us; speedup 1.0000x reference)
//
#include <hip/hip_runtime.h>

#define D 16

typedef short bf16x8 __attribute__((ext_vector_type(8)));
typedef float f32x16 __attribute__((ext_vector_type(16)));
typedef float v2f __attribute__((ext_vector_type(2)));

// f32 -> bf16 round-to-nearest-even
__device__ __forceinline__ short f2bf(float f) {
    unsigned u = __float_as_uint(f);
    unsigned r = u + 0x7FFFu + ((u >> 16) & 1u);
    return (short)(r >> 16);
}

// TWO problems per wave (software dual-issue to fill latency stalls).
// Per problem: 16-row (inc-1) f32 LDS tile (32 KB), written by
// mfma_f32_32x32x16_bf16 (half the 32-row acc stored per phase, recomputed
// for the other half); deferred-base row scan (r11 algebra) with r10 TOUCH
// discipline; all per-row ops of the two problems interleaved.
__global__ __launch_bounds__(64, 1)
void sig_pde_kernel(const float* __restrict__ X, const float* __restrict__ Y,
                    float* __restrict__ out) {
    __shared__ float sinc[2 * 16 * 512];    // 64 KB: two 16-row tiles

    const int bid  = blockIdx.x;            // 192 blocks
    const int idx0 = 2 * bid;
    const int idx1 = idx0 + 1;

    const int pair0 = idx0 >> 7, a0 = idx0 & 127;
    const int pair1 = idx1 >> 7, a1 = idx1 & 127;
    const float* prow0 = ((pair0 == 1) ? Y : X) + (size_t)a0 * 512 * D;
    const float* qrow0 = ((pair0 == 0) ? X : Y) + (size_t)a0 * 512 * D;
    const float* prow1 = ((pair1 == 1) ? Y : X) + (size_t)a1 * 512 * D;
    const float* qrow1 = ((pair1 == 0) ? X : Y) + (size_t)a1 * 512 * D;

    float* lds0 = sinc;
    float* lds1 = sinc + 16 * 512;

    const int l  = threadIdx.x;
    const int lm = l & 31;
    const int kh = l >> 5;                  // K-half of the fragment
    const int d0 = kh * 8;                  // lane's dim offset
    const int l7 = l & 7;
    const bool lane0 = (l == 0);
    const int rot = (l >> 2) & 7;           // read-side rotation (0-conflict)

    // ---- B fragments: 16 column tiles of dY per problem (128 VGPRs) ----
    bf16x8 Bf0[16], Bf1[16];
    #pragma unroll
    for (int n = 0; n < 16; ++n) {
        int jj = 32 * n + lm - 1;
        if (jj < 0) jj = 0;                 // col 0 garbage (masked in scan)
        {
            const float4* y1 = (const float4*)(qrow0 + (size_t)(jj + 1) * D + d0);
            const float4* y0 = (const float4*)(qrow0 + (size_t)jj * D + d0);
            float4 h1 = y1[0], h0 = y0[0], g1 = y1[1], g0 = y0[1];
            bf16x8 f;
            f[0] = f2bf(h1.x - h0.x); f[1] = f2bf(h1.y - h0.y);
            f[2] = f2bf(h1.z - h0.z); f[3] = f2bf(h1.w - h0.w);
            f[4] = f2bf(g1.x - g0.x); f[5] = f2bf(g1.y - g0.y);
            f[6] = f2bf(g1.z - g0.z); f[7] = f2bf(g1.w - g0.w);
            Bf0[n] = f;
        }
        {
            const float4* y1 = (const float4*)(qrow1 + (size_t)(jj + 1) * D + d0);
            const float4* y0 = (const float4*)(qrow1 + (size_t)jj * D + d0);
            float4 h1 = y1[0], h0 = y0[0], g1 = y1[1], g0 = y0[1];
            bf16x8 f;
            f[0] = f2bf(h1.x - h0.x); f[1] = f2bf(h1.y - h0.y);
            f[2] = f2bf(h1.z - h0.z); f[3] = f2bf(h1.w - h0.w);
            f[4] = f2bf(g1.x - g0.x); f[5] = f2bf(g1.y - g0.y);
            f[6] = f2bf(g1.z - g0.z); f[7] = f2bf(g1.w - g0.w);
            Bf1[n] = f;
        }
    }

    auto loadA = [&](const float* prow, int b) -> bf16x8 {
        int ii = 32 * b + lm - 1;
        if (ii < 0) ii = 0;                 // row 0 garbage (never scanned)
        const float4* x1 = (const float4*)(prow + (size_t)(ii + 1) * D + d0);
        const float4* x0 = (const float4*)(prow + (size_t)ii * D + d0);
        float4 h1 = x1[0], h0 = x0[0], g1 = x1[1], g0 = x0[1];
        bf16x8 f;
        f[0] = f2bf(h1.x - h0.x); f[1] = f2bf(h1.y - h0.y);
        f[2] = f2bf(h1.z - h0.z); f[3] = f2bf(h1.w - h0.w);
        f[4] = f2bf(g1.x - g0.x); f[5] = f2bf(g1.y - g0.y);
        f[6] = f2bf(g1.z - g0.z); f[7] = f2bf(g1.w - g0.w);
        return f;
    };

    // per-lane swizzled read offsets (bytes) within a tile row
    int ea4[8];
    #pragma unroll
    for (int m = 0; m < 8; ++m) ea4[m] = (8 * l + ((m + rot) & 7)) * 4;

    // GEMM write bases (floats): local row 4*kh, col group lm&~7
    float* wb0 = lds0 + kh * 2048 + (lm & ~7);
    float* wb1 = lds1 + kh * 2048 + (lm & ~7);

    // ---- scan state ----
    float s0[8], s1[8];
    #pragma unroll
    for (int m = 0; m < 8; ++m) { s0[m] = 0.0f; s1[m] = 0.0f; }
    float B0 = 1.0f, B1 = 1.0f;
    v2f gh0[8], gh1[8];
    float eA0[8], eB0[8], eA1[8], eB1[8];

    const f32x16 accC = {-1.f,-1.f,-1.f,-1.f,-1.f,-1.f,-1.f,-1.f,
                         -1.f,-1.f,-1.f,-1.f,-1.f,-1.f,-1.f,-1.f};

#define PREF1(BUF, LDSP, RB) do {                                             \
        const char* pb_ = (const char*)(LDSP) + (RB);                         \
        _Pragma("unroll")                                                     \
        for (int m_ = 0; m_ < 8; ++m_)                                        \
            BUF[m_] = *(const float*)(pb_ + ea4[m_]);                         \
    } while (0)

#define TOUCH(BUF) do { float tt_ = BUF[7];                                   \
        asm volatile("" : "+v"(tt_)); BUF[7] = tt_; } while (0)

#define GHBUILD1(GH, S, E) do {                                               \
        float gp_ = E[0] + 1.0f;  gp_ = lane0 ? 0.0f : gp_;                   \
        float gc_ = lane0 ? 0.0f : S[0];                                      \
        GH[0][0] = gp_; GH[0][1] = gc_;                                       \
        _Pragma("unroll")                                                     \
        for (int m_ = 1; m_ < 8; ++m_) {                                      \
            v2f pc_;                                                          \
            pc_[0] = E[m_] + 1.0f;                                            \
            pc_[1] = fmaf(S[m_ - 1], E[m_], S[m_]);                          \
            GH[m_] = GH[m_ - 1] + pc_;                                        \
        }                                                                     \
    } while (0)

#define SFMA1(S, BB, GH) do {                                                 \
        _Pragma("unroll")                                                     \
        for (int m_ = 0; m_ < 8; ++m_)                                        \
            S[m_] = fmaf(BB, GH[m_][0], GH[m_][1]);                           \
    } while (0)

#define DPP2(X0, X1, CTRL, RM, BC) do {                                       \
        int u0_ = __builtin_amdgcn_update_dpp(0, __float_as_int(X0), CTRL, RM, 0xF, BC); \
        int u1_ = __builtin_amdgcn_update_dpp(0, __float_as_int(X1), CTRL, RM, 0xF, BC); \
        X0 += __int_as_float(u0_); X1 += __int_as_float(u1_);                 \
    } while (0)

#define ISCAN2(X0, X1) do {                                                   \
        DPP2(X0, X1, 0x111, 0xF, true);                                       \
        DPP2(X0, X1, 0x112, 0xF, true);                                       \
        DPP2(X0, X1, 0x114, 0xF, true);                                       \
        DPP2(X0, X1, 0x118, 0xF, true);                                       \
        DPP2(X0, X1, 0x142, 0xA, false);                                      \
        DPP2(X0, X1, 0x143, 0xC, false);                                      \
    } while (0)

#define STEPROW2(EN0, EN1, EP0, EP1, RP) do {                                 \
        TOUCH(EN0); TOUCH(EN1);                                               \
        SFMA1(s0, B0, gh0); SFMA1(s1, B1, gh1);                               \
        float S0_ = s0[7], S1_ = s1[7];                                       \
        float W0_ = S0_, W1_ = S1_;                                           \
        ISCAN2(W0_, W1_);                                                     \
        PREF1(EP0, lds0, RP); PREF1(EP1, lds1, RP);                           \
        GHBUILD1(gh0, s0, EN0); GHBUILD1(gh1, s1, EN1);                       \
        B0 = 1.0f + (W0_ - S0_); B1 = 1.0f + (W1_ - S1_);                     \
    } while (0)

#define TAILROW2() do {                                                       \
        SFMA1(s0, B0, gh0); SFMA1(s1, B1, gh1);                               \
        float S0_ = s0[7], S1_ = s1[7];                                       \
        float W0_ = S0_, W1_ = S1_;                                           \
        ISCAN2(W0_, W1_);                                                     \
        B0 = 1.0f + (W0_ - S0_); B1 = 1.0f + (W1_ - S1_);                     \
    } while (0)

// GEMM phase: write half H (local rows 0..15 of grid rows 32b+16H..+15)
#define GEMM_PHASE(H) do {                                                    \
        _Pragma("unroll")                                                     \
        for (int n_ = 0; n_ < 16; ++n_) {                                     \
            f32x16 c0_ = __builtin_amdgcn_mfma_f32_32x32x16_bf16(Acur0, Bf0[n_], accC, 0, 0, 0); \
            f32x16 c1_ = __builtin_amdgcn_mfma_f32_32x32x16_bf16(Acur1, Bf1[n_], accC, 0, 0, 0); \
            float* q0_ = wb0 + 32 * n_ + ((l7 + n_) & 7);                     \
            float* q1_ = wb1 + 32 * n_ + ((l7 + n_) & 7);                     \
            _Pragma("unroll")                                                 \
            for (int r_ = 0; r_ < 8; ++r_) {                                  \
                const int off_ = (r_ & 3) * 512 + (r_ >> 2) * 4096;           \
                q0_[off_] = c0_[8 * (H) + r_];                                \
                q1_[off_] = c1_[8 * (H) + r_];                                \
            }                                                                 \
        }                                                                     \
    } while (0)

// scan local rows R0..15 (R0 is a literal 0 or 1)
#define SCAN_PHASE(R0) do {                                                   \
        PREF1(eA0, lds0, (R0) * 2048); PREF1(eA1, lds1, (R0) * 2048);         \
        GHBUILD1(gh0, s0, eA0); GHBUILD1(gh1, s1, eA1);                       \
        PREF1(eB0, lds0, ((R0) + 1) * 2048); PREF1(eB1, lds1, ((R0) + 1) * 2048); \
        _Pragma("unroll")                                                     \
        for (int r_ = (R0); r_ <= 14; ++r_) {                                 \
            const int rp_ = (r_ + 2 <= 15 ? r_ + 2 : 15) * 2048;              \
            if (((r_ - (R0)) & 1) == 0) STEPROW2(eB0, eB1, eA0, eA1, rp_);    \
            else                        STEPROW2(eA0, eA1, eB0, eB1, rp_);    \
        }                                                                     \
        TAILROW2();                                                           \
    } while (0)

    bf16x8 Acur0 = loadA(prow0, 0);
    bf16x8 Acur1 = loadA(prow1, 0);

    // block 0 (grid rows 0..31); grid row 0 skipped
    GEMM_PHASE(0);
    SCAN_PHASE(1);
    GEMM_PHASE(1);
    Acur0 = loadA(prow0, 1); Acur1 = loadA(prow1, 1);
    SCAN_PHASE(0);

    for (int b = 1; b < 16; ++b) {
        GEMM_PHASE(0);
        SCAN_PHASE(0);
        GEMM_PHASE(1);
        if (b < 15) { Acur0 = loadA(prow0, b + 1); Acur1 = loadA(prow1, b + 1); }
        SCAN_PHASE(0);
    }

#undef SCAN_PHASE
#undef GEMM_PHASE
#undef TAILROW2
#undef STEPROW2
#undef ISCAN2
#undef DPP2
#undef SFMA1
#undef GHBUILD1
#undef TOUCH
#undef PREF1

    // K[511][511] = lane 63: B + s[7]
    if (l == 63) { out[idx0] = B0 + s0[7]; out[idx1] = B1 + s1[7]; }
}

__global__ void sig_reduce_kernel(const float* __restrict__ ws,
                                  float* __restrict__ out) {
    const int a = threadIdx.x;  // 128 threads
    float v = ws[a] + ws[128 + a] - 2.0f * ws[256 + a];
    #pragma unroll
    for (int off = 32; off >= 1; off >>= 1) v += __shfl_down(v, off, 64);
    __shared__ float partial[2];
    if ((a & 63) == 0) partial[a >> 6] = v;
    __syncthreads();
    if (a == 0) out[0] = (partial[0] + partial[1]) * (1.0f / 128.0f);
}

extern "C" void kernel_launch(void* const* d_in, const int* in_sizes, int n_in,
                              void* d_out, int out_size, void* d_ws, size_t ws_size,
                              hipStream_t stream) {
    const float* X = (const float*)d_in[0];
    const float* Y = (const float*)d_in[1];
    float* out = (float*)d_out;
    float* ws  = (float*)d_ws;   // 384 floats: [pair*128 + a]

    sig_pde_kernel<<<dim3(192), dim3(64), 0, stream>>>(X, Y, ws);
    sig_reduce_kernel<<<dim3(1), dim3(128), 0, stream>>>(ws, out);
}